// Round 10
// baseline (1281.767 us; speedup 1.0000x reference)
//
#include <hip/hip_runtime.h>
#include <hip/hip_fp16.h>

// Kuramoto phase dynamics + coherence softmax. B*S=1024 rows, V=50257, 10 steps.
// ROTATION FORMULATION: state per element is (sin p, cos p) packed as 2xf16
// (RTN) in one u32 -- NOT the phase. Per step:
//   eps = dtc*(s*C - c*S)                                (|eps| ~ 1e-6)
//   (s,c) <- rotate by 0.1*omega (precomputed f32 table in d_ws, L2-hot)
//   (s,c) <- (s + eps*c, c - eps*s)                      (1st order, err eps^2/2)
// => ZERO transcendentals in the hot loop, no omega loads (table instead).
// Mean trick: sum_i eps_i = dC*S - dS*C = 0 exactly in the lagged scheme, so
// mean(p_final) = mean(p0) + mean(omega), computed at init; coherence =
// c*cos(M) + s*sin(M) from the final state. Phases never needed.
// State budget: 40 elems in 40 VGPRs (allocator pins 84 @ 768t: r5/r8/r9) +
// 26 planes in 79.9 KB LDS -> TWO blocks/CU (24 waves, 2x r7's latency hiding).
// f16 RTN round-trip error ~8e-4 on coherence -> ~8e-8 on output; + lag error
// 2.4e-7 (validated r7) stays well under the 6.6e-7 threshold.

#define V_DIM   50257
#define NROWS   1024
#define NT      768
#define NREGE   40               // register planes 0..39
#define NLPF    25               // full LDS planes (40..64)
#define TAILN   337              // plane 65 valid lanes
#define INV2PI  0.15915494309189535f

__device__ __forceinline__ float fsin(float r) { return __builtin_amdgcn_sinf(r); }
__device__ __forceinline__ float fcos(float r) { return __builtin_amdgcn_cosf(r); }
#define FENCE() __builtin_amdgcn_sched_barrier(0)

// ---- table init: tbl[j] = (sin(0.1*w_j), cos(0.1*w_j)) in f32 ----
__global__ void tbl_init_kernel(const float* __restrict__ omega,
                                float2* __restrict__ tbl) {
    const int j = blockIdx.x * 256 + threadIdx.x;
    if (j < V_DIM) {
        const float r = (0.1f * INV2PI) * omega[j];
        tbl[j] = make_float2(fsin(r), fcos(r));
    }
}

__device__ __forceinline__ void wave_red(float& a) {
    #pragma unroll
    for (int off = 32; off > 0; off >>= 1) a += __shfl_xor(a, off, 64);
}

__device__ __forceinline__ void block_reduce2(float& a, float& b, float* red) {
    wave_red(a); wave_red(b);
    const int wid = threadIdx.x >> 6;
    if ((threadIdx.x & 63) == 0) { red[wid] = a; red[16 + wid] = b; }
    __syncthreads();
    float ta = 0.f, tb = 0.f;
    #pragma unroll
    for (int i = 0; i < NT / 64; ++i) { ta += red[i]; tb += red[16 + i]; }
    a = ta; b = tb;
}

__device__ __forceinline__ void block_reduce3(float& a, float& b, float& c, float* red) {
    wave_red(a); wave_red(b); wave_red(c);
    const int wid = threadIdx.x >> 6;
    if ((threadIdx.x & 63) == 0) { red[wid] = a; red[16 + wid] = b; red[32 + wid] = c; }
    __syncthreads();
    float ta = 0.f, tb = 0.f, tc = 0.f;
    #pragma unroll
    for (int i = 0; i < NT / 64; ++i) { ta += red[i]; tb += red[16 + i]; tc += red[32 + i]; }
    a = ta; b = tb; c = tc;
}

template<bool ACC>
__device__ __forceinline__ __half2 rot_step(const __half2 sc, const float2 t,
                                            const float dC, const float dS,
                                            float& as, float& ac) {
    const float s = __low2float(sc), c = __high2float(sc);
    const float eps = __builtin_fmaf(s, dC, -(c * dS));   // pre-update s,c
    const float s1 = __builtin_fmaf(s, t.y, c * t.x);     // rotate by 0.1*w
    const float c1 = __builtin_fmaf(c, t.y, -(s * t.x));
    const float s2 = __builtin_fmaf(eps, c1, s1);         // rotate by eps (1st ord)
    const float c2 = __builtin_fmaf(-eps, s1, c1);
    if (ACC) { as += s2; ac += c2; }
    return __floats2half2_rn(s2, c2);
}

__global__ __launch_bounds__(NT)
void kuramoto_kernel(const float* __restrict__ logits,
                     const float* __restrict__ omega,
                     const float* __restrict__ noise,
                     float* __restrict__ out,
                     const float2* __restrict__ tbl) {
    __shared__ __half2 pls[NLPF + 1][NT];   // 79,872 B (plane 25 = tail)
    __shared__ float red[2][48];            // 384 B

    const int tid = threadIdx.x;
    const size_t base = (size_t)blockIdx.x * V_DIM;
    const float* __restrict__ lg = logits + base;
    const float* __restrict__ nz = noise + base;
    float* __restrict__ op = out + base;

    const float dtc = 0.1f * (0.1f / (float)V_DIM);
    int rp = 0;

    // ---- init: s,c = sincos(p0); sums of s, c, and (p0 + omega) ----
    __half2 sc[NREGE];
    float ss = 0.f, cc = 0.f, ms = 0.f;
    #pragma unroll
    for (int k = 0; k < NREGE; ++k) {
        const int e = k * NT + tid;
        const float p0 = __builtin_fmaf(0.1f, lg[e], nz[e]);
        const float r = p0 * INV2PI;
        const float s = fsin(r), c = fcos(r);
        ss += s; cc += c; ms += p0 + omega[e];
        sc[k] = __floats2half2_rn(s, c);
        if ((k & 3) == 3) FENCE();
    }
    #pragma unroll 4
    for (int j = 0; j < NLPF; ++j) {
        const int e = (NREGE + j) * NT + tid;
        const float p0 = __builtin_fmaf(0.1f, lg[e], nz[e]);
        const float r = p0 * INV2PI;
        const float s = fsin(r), c = fcos(r);
        ss += s; cc += c; ms += p0 + omega[e];
        pls[j][tid] = __floats2half2_rn(s, c);
    }
    if (tid < TAILN) {
        const int e = (NREGE + NLPF) * NT + tid;
        const float p0 = __builtin_fmaf(0.1f, lg[e], nz[e]);
        const float r = p0 * INV2PI;
        const float s = fsin(r), c = fcos(r);
        ss += s; cc += c; ms += p0 + omega[e];
        pls[NLPF][tid] = __floats2half2_rn(s, c);
    }
    block_reduce3(ss, cc, ms, red[rp]); rp ^= 1;
    float S = ss, C = cc;
    const float M = ms / (float)V_DIM;      // exact mean of final phases

    // ---- steps 0..8: rotate + accumulate new sums (lagged scheme) ----
    for (int st = 0; st < 9; ++st) {
        const float dC = dtc * C, dS = dtc * S;
        float ns = 0.f, nc = 0.f;
        #pragma unroll
        for (int k = 0; k < NREGE; ++k) {
            const float2 t = tbl[k * NT + tid];
            sc[k] = rot_step<true>(sc[k], t, dC, dS, ns, nc);
            if ((k & 3) == 3) FENCE();
        }
        #pragma unroll 4
        for (int j = 0; j < NLPF; ++j) {
            const float2 t = tbl[(NREGE + j) * NT + tid];
            pls[j][tid] = rot_step<true>(pls[j][tid], t, dC, dS, ns, nc);
        }
        if (tid < TAILN) {
            const float2 t = tbl[(NREGE + NLPF) * NT + tid];
            pls[NLPF][tid] = rot_step<true>(pls[NLPF][tid], t, dC, dS, ns, nc);
        }
        block_reduce2(ns, nc, red[rp]); rp ^= 1;
        S = ns; C = nc;
    }

    // ---- step 9: rotate only (sums no longer needed) ----
    {
        const float dC = dtc * C, dS = dtc * S;
        float du = 0.f, dv = 0.f;
        #pragma unroll
        for (int k = 0; k < NREGE; ++k) {
            const float2 t = tbl[k * NT + tid];
            sc[k] = rot_step<false>(sc[k], t, dC, dS, du, dv);
            if ((k & 3) == 3) FENCE();
        }
        #pragma unroll 4
        for (int j = 0; j < NLPF; ++j) {
            const float2 t = tbl[(NREGE + j) * NT + tid];
            pls[j][tid] = rot_step<false>(pls[j][tid], t, dC, dS, du, dv);
        }
        if (tid < TAILN) {
            const float2 t = tbl[(NREGE + NLPF) * NT + tid];
            pls[NLPF][tid] = rot_step<false>(pls[NLPF][tid], t, dC, dS, du, dv);
        }
    }

    // ---- epilogue: coh = c*cosM + s*sinM; e = exp(coh); softmax ----
    const float cM = fcos(M * INV2PI), sM = fsin(M * INV2PI);
    float es = 0.f, dd = 0.f;
    #pragma unroll
    for (int k = 0; k < NREGE; ++k) {
        const float s = __low2float(sc[k]), c = __high2float(sc[k]);
        const float e = __expf(__builtin_fmaf(c, cM, s * sM));
        es += e;
        sc[k] = __builtin_bit_cast(__half2, e);   // stash f32 e in the slot
        if ((k & 3) == 3) FENCE();
    }
    #pragma unroll 4
    for (int j = 0; j < NLPF; ++j) {
        const __half2 h = pls[j][tid];
        const float s = __low2float(h), c = __high2float(h);
        const float e = __expf(__builtin_fmaf(c, cM, s * sM));
        es += e;
        pls[j][tid] = __builtin_bit_cast(__half2, e);
    }
    if (tid < TAILN) {
        const __half2 h = pls[NLPF][tid];
        const float s = __low2float(h), c = __high2float(h);
        const float e = __expf(__builtin_fmaf(c, cM, s * sM));
        es += e;
        pls[NLPF][tid] = __builtin_bit_cast(__half2, e);
    }
    block_reduce2(es, dd, red[rp]); rp ^= 1;
    const float inv = 1.f / es;

    #pragma unroll
    for (int k = 0; k < NREGE; ++k) {
        op[k * NT + tid] = __builtin_bit_cast(float, sc[k]) * inv;
        if ((k & 3) == 3) FENCE();
    }
    #pragma unroll 4
    for (int j = 0; j < NLPF; ++j) {
        op[(NREGE + j) * NT + tid] = __builtin_bit_cast(float, pls[j][tid]) * inv;
    }
    if (tid < TAILN) {
        op[(NREGE + NLPF) * NT + tid] = __builtin_bit_cast(float, pls[NLPF][tid]) * inv;
    }
}

extern "C" void kernel_launch(void* const* d_in, const int* in_sizes, int n_in,
                              void* d_out, int out_size, void* d_ws, size_t ws_size,
                              hipStream_t stream) {
    const float* logits = (const float*)d_in[0];
    const float* omega  = (const float*)d_in[1];  // natural_frequencies [V]
    const float* noise  = (const float*)d_in[2];
    float* out = (float*)d_out;
    float2* tbl = (float2*)d_ws;                  // 402,056 B needed
    (void)in_sizes; (void)n_in; (void)out_size; (void)ws_size;

    tbl_init_kernel<<<(V_DIM + 255) / 256, 256, 0, stream>>>(omega, tbl);
    kuramoto_kernel<<<NROWS, NT, 0, stream>>>(logits, omega, noise, out, tbl);
}

// Round 11
// 384.273 us; speedup vs baseline: 3.3356x; 3.3356x over previous
//
#include <hip/hip_runtime.h>
#include <hip/hip_fp16.h>

// Kuramoto phase dynamics + coherence softmax. B*S=1024 rows, V=50257, 10 steps.
// TWO-PASS TRAJECTORY SCHEME (no per-step state, no per-step barriers):
//   The coupling term eps = dtc*(s*C - c*S) <= ~6e-3 rad/step only perturbs
//   phases; row sums S_t,C_t computed from UNCOUPLED trajectories (pure
//   rotation by 0.1*omega/step) are accurate to ~0.6%/step -> phase error
//   ~2e-6 rad -> ~4e-8 output error (threshold 6.6e-7, fp floor 2.4e-7).
// Pass A: (s0,c0)=sincos(p0) -> state (half2, 4 B/elem); rotate 10 steps via
//         half2 table (sin .1w, cos .1w - 1), accumulate S_t,C_t (+Sum p0,
//         Sum w for the exact mean: sum_i eps_i(t) == 0 identically).
// One 22-value block reduce (the ONLY barriers). Sums -> SGPR (readfirstlane).
// Pass B: re-rotate from state, eps = sum_t (s_t*dC_t - c_t*dS_t), exact
//         eps-rotation, coh = c*cosM + s*sinM, e = exp(coh) stashed (f32 bits)
//         over the state slot. esum reduce. Pass C: out = e * inv.
// State budget obeys the pinned 84-VGPR @768t allocation (r5-r10 evidence):
//   16 elems in regs (sc[16]) + 50 planes in LDS (153.6 KB, [j][tid]
//   thread-private columns, 2-way bank alias = free). 20 accumulators + ~25
//   transient temps ~ 63 regs peak. 12 waves/CU.
// f16 costs: state round-trip once (~5e-4 -> 1e-8 out), table angle error
// ~2.4e-4 rad/step*10 (~5e-8 out). All well under threshold.

#define V_DIM  50257
#define NROWS  1024
#define NT     768
#define NRE    16             // register planes 0..15
#define NLP    50             // LDS planes 16..65 (last partial)
#define TAILN  337            // valid lanes of plane 65
#define NSTEP  10
#define INV2PI 0.15915494309189535f
#define DTC    (0.1f * (0.1f / (float)V_DIM))   // DT * coupling

__device__ __forceinline__ float fsin(float r) { return __builtin_amdgcn_sinf(r); }
__device__ __forceinline__ float fcos(float r) { return __builtin_amdgcn_cosf(r); }
__device__ __forceinline__ float rfl(float x) {
    return __builtin_bit_cast(float, __builtin_amdgcn_readfirstlane(__builtin_bit_cast(int, x)));
}
#define FENCE() __builtin_amdgcn_sched_barrier(0)

// tbl[j] = (sin(0.1*w_j), cos(0.1*w_j) - 1) in half2 (201 KB, L2-resident).
__global__ void tbl_kernel(const float* __restrict__ omega, __half2* __restrict__ tbl) {
    const int j = blockIdx.x * 256 + threadIdx.x;
    if (j < V_DIM) {
        const float th = (0.1f * INV2PI) * omega[j];
        tbl[j] = __floats2half2_rn(fsin(th), fcos(th) - 1.0f);
    }
}

__global__ __launch_bounds__(NT)
void kuramoto_kernel(const float* __restrict__ lg_,
                     const float* __restrict__ om_,
                     const float* __restrict__ nz_,
                     float* __restrict__ out_,
                     const __half2* __restrict__ tbl) {
    __shared__ __half2 st[NLP][NT];      // 153,600 B
    __shared__ float redA[22][12];       // 1,056 B
    __shared__ float redB[12];           // 48 B

    const int tid = threadIdx.x;
    const size_t base = (size_t)blockIdx.x * V_DIM;
    const float* __restrict__ lg = lg_ + base;
    const float* __restrict__ nz = nz_ + base;
    float* __restrict__ op = out_ + base;

    float vS[NSTEP], vC[NSTEP];
    #pragma unroll
    for (int t = 0; t < NSTEP; ++t) { vS[t] = 0.f; vC[t] = 0.f; }
    float sp0 = 0.f, sw = 0.f;
    __half2 sc[NRE];

    // ---------------- pass A ----------------
    auto passA = [&](int e) -> __half2 {
        const float p0 = __builtin_fmaf(0.1f, lg[e], nz[e]);
        sp0 += p0; sw += om_[e];
        const float r = p0 * INV2PI;
        float s = fsin(r), c = fcos(r);
        const __half2 h0 = __floats2half2_rn(s, c);
        const __half2 th = tbl[e];
        const float ts = __low2float(th), td = __high2float(th);
        #pragma unroll
        for (int t = 0; t < NSTEP; ++t) {
            vS[t] += s; vC[t] += c;
            float u = __builtin_fmaf(s, td, s); u = __builtin_fmaf(c, ts, u);
            float v = __builtin_fmaf(c, td, c); v = __builtin_fmaf(-s, ts, v);
            s = u; c = v;
        }
        return h0;
    };
    #pragma unroll
    for (int k = 0; k < NRE; ++k) {
        sc[k] = passA(k * NT + tid);
        if (k & 1) FENCE();
    }
    #pragma unroll 2
    for (int j = 0; j < NLP - 1; ++j) {
        st[j][tid] = passA((NRE + j) * NT + tid);
    }
    if (tid < TAILN) st[NLP - 1][tid] = passA((NRE + NLP - 1) * NT + tid);

    // ---------------- reduce 22 values ----------------
    #pragma unroll
    for (int off = 32; off > 0; off >>= 1) {
        #pragma unroll
        for (int t = 0; t < NSTEP; ++t) {
            vS[t] += __shfl_xor(vS[t], off, 64);
            vC[t] += __shfl_xor(vC[t], off, 64);
        }
        sp0 += __shfl_xor(sp0, off, 64);
        sw  += __shfl_xor(sw, off, 64);
    }
    const int wid = tid >> 6;
    if ((tid & 63) == 0) {
        #pragma unroll
        for (int t = 0; t < NSTEP; ++t) { redA[t][wid] = vS[t]; redA[NSTEP + t][wid] = vC[t]; }
        redA[20][wid] = sp0; redA[21][wid] = sw;
    }
    __syncthreads();
    float dSt[NSTEP], dCt[NSTEP];
    float cM, sM;
    {
        #pragma unroll
        for (int t = 0; t < NSTEP; ++t) {
            float a = 0.f, b = 0.f;
            #pragma unroll
            for (int i = 0; i < NT / 64; ++i) { a += redA[t][i]; b += redA[NSTEP + t][i]; }
            dSt[t] = rfl(DTC * a);
            dCt[t] = rfl(DTC * b);
        }
        float a = 0.f, b = 0.f;
        #pragma unroll
        for (int i = 0; i < NT / 64; ++i) { a += redA[20][i]; b += redA[21][i]; }
        const float M = (a + b) / (float)V_DIM;   // mean(p_final) exactly
        const float rM = M * INV2PI;
        cM = fcos(rM); sM = fsin(rM);
    }

    // ---------------- pass B ----------------
    float esum = 0.f;
    auto passB = [&](__half2 h0, int e) -> float {
        float s = __low2float(h0), c = __high2float(h0);
        const __half2 th = tbl[e];
        const float ts = __low2float(th), td = __high2float(th);
        float eps = 0.f;
        #pragma unroll
        for (int t = 0; t < NSTEP; ++t) {
            eps = __builtin_fmaf(s, dCt[t], eps);
            eps = __builtin_fmaf(-c, dSt[t], eps);
            float u = __builtin_fmaf(s, td, s); u = __builtin_fmaf(c, ts, u);
            float v = __builtin_fmaf(c, td, c); v = __builtin_fmaf(-s, ts, v);
            s = u; c = v;
        }
        const float re = eps * INV2PI;
        const float se = fsin(re), ce = fcos(re);
        const float s2 = __builtin_fmaf(s, ce, c * se);
        const float c2 = __builtin_fmaf(c, ce, -(s * se));
        const float coh = __builtin_fmaf(c2, cM, s2 * sM);
        const float ev = __expf(coh);
        esum += ev;
        return ev;
    };
    #pragma unroll
    for (int k = 0; k < NRE; ++k) {
        sc[k] = __builtin_bit_cast(__half2, passB(sc[k], k * NT + tid));
        if (k & 1) FENCE();
    }
    #pragma unroll 2
    for (int j = 0; j < NLP - 1; ++j) {
        st[j][tid] = __builtin_bit_cast(__half2, passB(st[j][tid], (NRE + j) * NT + tid));
    }
    if (tid < TAILN) {
        st[NLP - 1][tid] = __builtin_bit_cast(__half2, passB(st[NLP - 1][tid], (NRE + NLP - 1) * NT + tid));
    }

    // ---------------- esum reduce ----------------
    #pragma unroll
    for (int off = 32; off > 0; off >>= 1) esum += __shfl_xor(esum, off, 64);
    if ((tid & 63) == 0) redB[wid] = esum;
    __syncthreads();
    float tot = 0.f;
    #pragma unroll
    for (int i = 0; i < NT / 64; ++i) tot += redB[i];
    const float inv = 1.f / tot;

    // ---------------- pass C: stores ----------------
    #pragma unroll
    for (int k = 0; k < NRE; ++k) {
        op[k * NT + tid] = __builtin_bit_cast(float, sc[k]) * inv;
    }
    #pragma unroll 2
    for (int j = 0; j < NLP - 1; ++j) {
        op[(NRE + j) * NT + tid] = __builtin_bit_cast(float, st[j][tid]) * inv;
    }
    if (tid < TAILN) {
        op[(NRE + NLP - 1) * NT + tid] = __builtin_bit_cast(float, st[NLP - 1][tid]) * inv;
    }
}

extern "C" void kernel_launch(void* const* d_in, const int* in_sizes, int n_in,
                              void* d_out, int out_size, void* d_ws, size_t ws_size,
                              hipStream_t stream) {
    const float* logits = (const float*)d_in[0];
    const float* omega  = (const float*)d_in[1];  // natural_frequencies [V]
    const float* noise  = (const float*)d_in[2];
    float* out = (float*)d_out;
    __half2* tbl = (__half2*)d_ws;                // 201,028 B needed
    (void)in_sizes; (void)n_in; (void)out_size; (void)ws_size;

    tbl_kernel<<<(V_DIM + 255) / 256, 256, 0, stream>>>(omega, tbl);
    kuramoto_kernel<<<NROWS, NT, 0, stream>>>(logits, omega, noise, out, tbl);
}

// Round 12
// 372.290 us; speedup vs baseline: 3.4429x; 1.0322x over previous
//
#include <hip/hip_runtime.h>
#include <hip/hip_fp16.h>

// Kuramoto phase dynamics + coherence softmax. B*S=1024 rows, V=50257, 10 steps.
// Two-pass trajectory scheme (validated r11, absmax 2.38e-7), now with PACKED
// f32 math: threads own adjacent element pairs (e=stripe+2*tid), rotation and
// eps arithmetic in ext_vector_type(2) floats -> v_pk_fma_f32 (full-rate on
// gfx950), halving VALU issue vs r11's scalar loops.
//   Pass A: (s0,c0)=sincos(p0) -> f16 pair state (8 B/pair); rotate 10 steps
//           via float4 table (ts0,ts1,td0,td1), accumulate S_t,C_t (horizontal
//           adds keep accumulators at 21 VGPRs; allocator pins 84 @ 768t).
//   Reduce 21 sums (one barrier). dSt/dCt -> SGPR via readfirstlane.
//   Pass B: re-rotate, eps = sum_t(s_t*dCt - c_t*dSt) (|eps|~4e-4), 1st-order
//           eps rotation, coh = c*cM + s*sM, e = exp(coh) stashed over state.
//   esum reduce (second barrier). Pass C: out = e*inv, float2 stores.
// Omega is never read per-element in the main kernel: Sum(omega) is
// row-invariant, computed once by a deterministic single-block kernel (ws[0]);
// mean(p_final) = (Sum p0 + Sum omega)/V since sum_i eps_i == 0 identically.
// Tail (elements 49152..50256) handled scalar with on-the-fly angles.

#define V_DIM   50257
#define NROWS   1024
#define NT      768
#define NSR     8                 // register pair-stripes (elems 0..12287)
#define NSL     24                // LDS pair-stripes     (elems 12288..49151)
#define NSTOT   (NSR + NSL)       // 32 stripes x 1536 elems = 49152
#define STRIDE  (2 * NT)          // 1536
#define P64_B   49152             // scalar plane, full
#define P65_B   49920             // scalar plane, first 337 lanes
#define TAILN   (V_DIM - P65_B)   // 337
#define NSTEP   10
#define INV2PI  0.15915494309189535f
#define DTC     (0.1f * (0.1f / (float)V_DIM))

typedef float v2f __attribute__((ext_vector_type(2)));

__device__ __forceinline__ float fsin(float r) { return __builtin_amdgcn_sinf(r); }
__device__ __forceinline__ float fcos(float r) { return __builtin_amdgcn_cosf(r); }
__device__ __forceinline__ float rfl(float x) {
    return __builtin_bit_cast(float, __builtin_amdgcn_readfirstlane(__builtin_bit_cast(int, x)));
}
#define FENCE() __builtin_amdgcn_sched_barrier(0)

__device__ __forceinline__ void rot2(v2f& s, v2f& c, const v2f ts, const v2f td) {
    v2f u = __builtin_elementwise_fma(s, td, s);
    u = __builtin_elementwise_fma(c, ts, u);
    v2f v = __builtin_elementwise_fma(c, td, c);
    v = __builtin_elementwise_fma(-s, ts, v);
    s = u; c = v;
}
__device__ __forceinline__ void rot1(float& s, float& c, const float ts, const float td) {
    float u = __builtin_fmaf(s, td, s); u = __builtin_fmaf(c, ts, u);
    float v = __builtin_fmaf(c, td, c); v = __builtin_fmaf(-s, ts, v);
    s = u; c = v;
}

// ---- ws[0] = sum(omega), deterministic single-block reduce ----
__global__ __launch_bounds__(1024) void sw_kernel(const float* __restrict__ om,
                                                  float* __restrict__ ws) {
    __shared__ float red[16];
    const int tid = threadIdx.x;
    float a = 0.f;
    for (int i = tid; i < V_DIM; i += 1024) a += om[i];
    #pragma unroll
    for (int off = 32; off > 0; off >>= 1) a += __shfl_xor(a, off, 64);
    if ((tid & 63) == 0) red[tid >> 6] = a;
    __syncthreads();
    if (tid == 0) {
        float t = 0.f;
        #pragma unroll
        for (int i = 0; i < 16; ++i) t += red[i];
        ws[0] = t;
    }
}

// ---- tbl4[q] = (sin(.1*w[2q]), sin(.1*w[2q+1]), cos(.1*w[2q])-1, cos(.1*w[2q+1])-1) ----
__global__ __launch_bounds__(256) void tbl_kernel(const float* __restrict__ om,
                                                  float4* __restrict__ tbl4) {
    const int q = blockIdx.x * 256 + threadIdx.x;
    if (q < NSTOT * NT) {
        const float t0 = (0.1f * INV2PI) * om[2 * q];
        const float t1 = (0.1f * INV2PI) * om[2 * q + 1];
        tbl4[q] = make_float4(fsin(t0), fsin(t1), fcos(t0) - 1.f, fcos(t1) - 1.f);
    }
}

__global__ __launch_bounds__(NT)
void kuramoto_kernel(const float* __restrict__ lg_,
                     const float* __restrict__ nz_,
                     const float* __restrict__ om_,
                     float* __restrict__ out_,
                     const float4* __restrict__ tbl4,
                     const float* __restrict__ swp) {
    __shared__ uint2 st[NSL][NT];        // 147,456 B : f16 pair state (s01,c01)
    __shared__ __half2 st64[NT];         // 3,072 B
    __shared__ __half2 st65[TAILN];      // 1,348 B
    __shared__ float redA[21][12];       // 1,008 B
    __shared__ float redB[12];

    const int tid = threadIdx.x;
    const size_t base = (size_t)blockIdx.x * V_DIM;
    const float* __restrict__ lg = lg_ + base;
    const float* __restrict__ nz = nz_ + base;
    float* __restrict__ op = out_ + base;

    float vS[NSTEP], vC[NSTEP];
    #pragma unroll
    for (int t = 0; t < NSTEP; ++t) { vS[t] = 0.f; vC[t] = 0.f; }
    float sp0 = 0.f;
    uint2 rst[NSR];
    float tts0, ttd0, tts1, ttd1;

    // ---------------- pass A ----------------
    auto passA = [&](int m) -> uint2 {
        const int e = m * STRIDE + 2 * tid;
        const v2f l = *(const v2f*)(lg + e);
        const v2f n = *(const v2f*)(nz + e);
        const v2f p0 = __builtin_elementwise_fma(v2f{0.1f, 0.1f}, l, n);
        sp0 += p0.x + p0.y;
        const float4 tb = tbl4[m * NT + tid];
        const v2f ts = {tb.x, tb.y}, td = {tb.z, tb.w};
        v2f s = {fsin(p0.x * INV2PI), fsin(p0.y * INV2PI)};
        v2f c = {fcos(p0.x * INV2PI), fcos(p0.y * INV2PI)};
        uint2 hp;
        hp.x = __builtin_bit_cast(unsigned, __floats2half2_rn(s.x, s.y));
        hp.y = __builtin_bit_cast(unsigned, __floats2half2_rn(c.x, c.y));
        #pragma unroll
        for (int t = 0; t < NSTEP; ++t) {
            vS[t] += s.x + s.y; vC[t] += c.x + c.y;
            rot2(s, c, ts, td);
        }
        return hp;
    };
    #pragma unroll
    for (int m = 0; m < NSR; ++m) { rst[m] = passA(m); FENCE(); }
    #pragma unroll 2
    for (int m = NSR; m < NSTOT; ++m) { st[m - NSR][tid] = passA(m); }
    {   // tail planes, scalar
        const int e0 = P64_B + tid;
        const float p0 = __builtin_fmaf(0.1f, lg[e0], nz[e0]);
        sp0 += p0;
        float s = fsin(p0 * INV2PI), c = fcos(p0 * INV2PI);
        st64[tid] = __floats2half2_rn(s, c);
        const float th = (0.1f * INV2PI) * om_[e0];
        tts0 = fsin(th); ttd0 = fcos(th) - 1.f;
        #pragma unroll
        for (int t = 0; t < NSTEP; ++t) { vS[t] += s; vC[t] += c; rot1(s, c, tts0, ttd0); }
        if (tid < TAILN) {
            const int e1 = P65_B + tid;
            const float q0 = __builtin_fmaf(0.1f, lg[e1], nz[e1]);
            sp0 += q0;
            float s1 = fsin(q0 * INV2PI), c1 = fcos(q0 * INV2PI);
            st65[tid] = __floats2half2_rn(s1, c1);
            const float th1 = (0.1f * INV2PI) * om_[e1];
            tts1 = fsin(th1); ttd1 = fcos(th1) - 1.f;
            #pragma unroll
            for (int t = 0; t < NSTEP; ++t) { vS[t] += s1; vC[t] += c1; rot1(s1, c1, tts1, ttd1); }
        }
    }

    // ---------------- reduce 21 values ----------------
    #pragma unroll
    for (int off = 32; off > 0; off >>= 1) {
        #pragma unroll
        for (int t = 0; t < NSTEP; ++t) {
            vS[t] += __shfl_xor(vS[t], off, 64);
            vC[t] += __shfl_xor(vC[t], off, 64);
        }
        sp0 += __shfl_xor(sp0, off, 64);
    }
    const int wid = tid >> 6;
    if ((tid & 63) == 0) {
        #pragma unroll
        for (int t = 0; t < NSTEP; ++t) { redA[t][wid] = vS[t]; redA[NSTEP + t][wid] = vC[t]; }
        redA[20][wid] = sp0;
    }
    __syncthreads();
    float dSt[NSTEP], dCt[NSTEP], cM, sM;
    {
        #pragma unroll
        for (int t = 0; t < NSTEP; ++t) {
            float a = 0.f, b = 0.f;
            #pragma unroll
            for (int i = 0; i < NT / 64; ++i) { a += redA[t][i]; b += redA[NSTEP + t][i]; }
            dSt[t] = rfl(DTC * a);
            dCt[t] = rfl(DTC * b);
        }
        float a = 0.f;
        #pragma unroll
        for (int i = 0; i < NT / 64; ++i) a += redA[20][i];
        const float M = (a + swp[0]) / (float)V_DIM;
        cM = rfl(fcos(M * INV2PI)); sM = rfl(fsin(M * INV2PI));
    }

    // ---------------- pass B ----------------
    float es = 0.f;
    auto passB = [&](uint2 hp, int m) -> uint2 {
        const __half2 hs = __builtin_bit_cast(__half2, hp.x);
        const __half2 hc = __builtin_bit_cast(__half2, hp.y);
        v2f s = {__low2float(hs), __high2float(hs)};
        v2f c = {__low2float(hc), __high2float(hc)};
        const float4 tb = tbl4[m * NT + tid];
        const v2f ts = {tb.x, tb.y}, td = {tb.z, tb.w};
        v2f eps = {0.f, 0.f};
        #pragma unroll
        for (int t = 0; t < NSTEP; ++t) {
            eps = __builtin_elementwise_fma(s, v2f{dCt[t], dCt[t]}, eps);
            eps = __builtin_elementwise_fma(-c, v2f{dSt[t], dSt[t]}, eps);
            rot2(s, c, ts, td);
        }
        const v2f s2 = __builtin_elementwise_fma(c, eps, s);      // 1st-order eps-rot
        const v2f c2 = __builtin_elementwise_fma(-s, eps, c);
        v2f coh = __builtin_elementwise_fma(s2, v2f{sM, sM}, v2f{0.f, 0.f});
        coh = __builtin_elementwise_fma(c2, v2f{cM, cM}, coh);
        const v2f ev = {__expf(coh.x), __expf(coh.y)};
        es += ev.x + ev.y;
        return __builtin_bit_cast(uint2, ev);                     // stash f32 pair
    };
    #pragma unroll
    for (int m = 0; m < NSR; ++m) { rst[m] = passB(rst[m], m); FENCE(); }
    #pragma unroll 2
    for (int m = NSR; m < NSTOT; ++m) { st[m - NSR][tid] = passB(st[m - NSR][tid], m); }
    {   // tail
        const __half2 h0 = st64[tid];
        float s = __low2float(h0), c = __high2float(h0);
        float ep = 0.f;
        #pragma unroll
        for (int t = 0; t < NSTEP; ++t) {
            ep = __builtin_fmaf(s, dCt[t], ep);
            ep = __builtin_fmaf(-c, dSt[t], ep);
            rot1(s, c, tts0, ttd0);
        }
        const float s2 = __builtin_fmaf(c, ep, s);
        const float c2 = __builtin_fmaf(-s, ep, c);
        const float e0 = __expf(__builtin_fmaf(c2, cM, s2 * sM));
        es += e0;
        st64[tid] = __builtin_bit_cast(__half2, e0);
        if (tid < TAILN) {
            const __half2 h1 = st65[tid];
            float s1 = __low2float(h1), c1 = __high2float(h1);
            float ep1 = 0.f;
            #pragma unroll
            for (int t = 0; t < NSTEP; ++t) {
                ep1 = __builtin_fmaf(s1, dCt[t], ep1);
                ep1 = __builtin_fmaf(-c1, dSt[t], ep1);
                rot1(s1, c1, tts1, ttd1);
            }
            const float s3 = __builtin_fmaf(c1, ep1, s1);
            const float c3 = __builtin_fmaf(-s1, ep1, c1);
            const float e1 = __expf(__builtin_fmaf(c3, cM, s3 * sM));
            es += e1;
            st65[tid] = __builtin_bit_cast(__half2, e1);
        }
    }

    // ---------------- esum reduce ----------------
    #pragma unroll
    for (int off = 32; off > 0; off >>= 1) es += __shfl_xor(es, off, 64);
    if ((tid & 63) == 0) redB[wid] = es;
    __syncthreads();
    float tot = 0.f;
    #pragma unroll
    for (int i = 0; i < NT / 64; ++i) tot += redB[i];
    const float inv = 1.f / tot;

    // ---------------- pass C: stores ----------------
    #pragma unroll
    for (int m = 0; m < NSR; ++m) {
        const v2f ev = __builtin_bit_cast(v2f, rst[m]);
        *(v2f*)(op + m * STRIDE + 2 * tid) = ev * inv;
    }
    #pragma unroll 2
    for (int m = NSR; m < NSTOT; ++m) {
        const v2f ev = __builtin_bit_cast(v2f, st[m - NSR][tid]);
        *(v2f*)(op + m * STRIDE + 2 * tid) = ev * inv;
    }
    op[P64_B + tid] = __builtin_bit_cast(float, st64[tid]) * inv;
    if (tid < TAILN) op[P65_B + tid] = __builtin_bit_cast(float, st65[tid]) * inv;
}

extern "C" void kernel_launch(void* const* d_in, const int* in_sizes, int n_in,
                              void* d_out, int out_size, void* d_ws, size_t ws_size,
                              hipStream_t stream) {
    const float* logits = (const float*)d_in[0];
    const float* omega  = (const float*)d_in[1];  // natural_frequencies [V]
    const float* noise  = (const float*)d_in[2];
    float* out = (float*)d_out;
    float* swp = (float*)d_ws;                          // ws[0] = sum(omega)
    float4* tbl4 = (float4*)((char*)d_ws + 16);         // 393,216 B
    (void)in_sizes; (void)n_in; (void)out_size; (void)ws_size;

    sw_kernel<<<1, 1024, 0, stream>>>(omega, swp);
    tbl_kernel<<<(NSTOT * NT + 255) / 256, 256, 0, stream>>>(omega, tbl4);
    kuramoto_kernel<<<NROWS, NT, 0, stream>>>(logits, noise, omega, out, tbl4, swp);
}